// Round 1
// baseline (1843.253 us; speedup 1.0000x reference)
//
#include <hip/hip_runtime.h>
#include <math.h>

// Problem constants (from reference)
#define EPSV 0.1f
#define MAX_ITER 10
constexpr int NB       = 16;    // batch n
constexpr int IN_SIZE  = 1024;
constexpr int IN_DIM   = 1024;
constexpr int HEADS    = 4;
constexpr int OUT_SIZE = 128;
constexpr int OUT_DIM  = 1024;

// ---------------------------------------------------------------------------
// Generic fp32 64x64-tile GEMM: C = alpha * A * op(B) (+bias, +relu)
// BT=true : B stored [N][K] row-major (C = A * B^T), k-contiguous loads
// BT=false: B stored [K][N] row-major (C = A * B)
// Batched via blockIdx.z with offset = (bz/div)*sN + (bz%div)*sM per operand.
// All dims assumed multiples of tile sizes (true for this problem).
// ---------------------------------------------------------------------------
template<bool BT, bool RELU>
__global__ __launch_bounds__(256)
void gemm_kernel(const float* __restrict__ A, const float* __restrict__ B,
                 const float* __restrict__ bias, float* __restrict__ C,
                 int K, int lda, int ldb, int ldc,
                 int div, long AsN, long AsM, long BsN, long BsM,
                 long CsN, long CsM, float alpha)
{
    const int bz = blockIdx.z;
    A += (long)(bz / div) * AsN + (long)(bz % div) * AsM;
    B += (long)(bz / div) * BsN + (long)(bz % div) * BsM;
    C += (long)(bz / div) * CsN + (long)(bz % div) * CsM;

    const int m0 = blockIdx.y * 64;
    const int n0 = blockIdx.x * 64;

    __shared__ float As[16][68];   // [k][m], padded: 68*4B row stride, 16B aligned
    __shared__ float Bs[16][68];   // [k][n]

    const int tid = threadIdx.x;
    const int tx = tid & 15;       // 0..15 -> n micro
    const int ty = tid >> 4;       // 0..15 -> m micro

    float acc[4][4] = {};

    for (int k0 = 0; k0 < K; k0 += 16) {
        // --- load A tile: rows m0..m0+63, k0..k0+15 (float4 along k) ---
        {
            const int r = tid >> 2;          // 0..63
            const int c = (tid & 3) * 4;     // 0,4,8,12
            const float4 av = *(const float4*)(A + (long)(m0 + r) * lda + k0 + c);
            As[c + 0][r] = av.x; As[c + 1][r] = av.y;
            As[c + 2][r] = av.z; As[c + 3][r] = av.w;
        }
        // --- load B tile ---
        if (BT) {
            const int r = tid >> 2;
            const int c = (tid & 3) * 4;
            const float4 bv = *(const float4*)(B + (long)(n0 + r) * ldb + k0 + c);
            Bs[c + 0][r] = bv.x; Bs[c + 1][r] = bv.y;
            Bs[c + 2][r] = bv.z; Bs[c + 3][r] = bv.w;
        } else {
            #pragma unroll
            for (int rep = 0; rep < 4; ++rep) {
                const int idx = rep * 256 + tid;
                const int kk = idx >> 6, nn = idx & 63;
                Bs[kk][nn] = B[(long)(k0 + kk) * ldb + n0 + nn];
            }
        }
        __syncthreads();

        #pragma unroll
        for (int kk = 0; kk < 16; ++kk) {
            const float4 a4 = *(const float4*)&As[kk][ty * 4];
            const float4 b4 = *(const float4*)&Bs[kk][tx * 4];
            const float a[4] = {a4.x, a4.y, a4.z, a4.w};
            const float b[4] = {b4.x, b4.y, b4.z, b4.w};
            #pragma unroll
            for (int i = 0; i < 4; ++i)
                #pragma unroll
                for (int j = 0; j < 4; ++j)
                    acc[i][j] = fmaf(a[i], b[j], acc[i][j]);
        }
        __syncthreads();
    }

    #pragma unroll
    for (int i = 0; i < 4; ++i) {
        const long m = m0 + ty * 4 + i;
        #pragma unroll
        for (int j = 0; j < 4; ++j) {
            const int n = n0 + tx * 4 + j;
            float val = acc[i][j] * alpha;
            if (RELU) { val += bias[n]; val = fmaxf(val, 0.f); }
            C[m * ldc + n] = val;
        }
    }
}

// ---------------------------------------------------------------------------
// Log-domain Sinkhorn: one block (1024 threads) per (n,m) tile, b = n*4+m.
// K tile element (i,s) lives at Kbuf[n*IN_SIZE*512 + i*512 + m*128 + s].
// Writes T transposed: Tt[b][s][i] = exp(K + u_i + v_s)  (coalesced over i),
// so the feat einsum becomes a plain NN GEMM.
// ---------------------------------------------------------------------------
__global__ __launch_bounds__(1024)
void sinkhorn_kernel(const float* __restrict__ Kbuf, float* __restrict__ Tt)
{
    const int b = blockIdx.x;          // 0..63
    const int n = b >> 2, m = b & 3;
    const float* Kt = Kbuf + (long)n * IN_SIZE * 512 + m * OUT_SIZE;
    const int t = threadIdx.x;

    __shared__ float u[IN_SIZE];
    __shared__ float v[OUT_SIZE];
    __shared__ float red[1024];

    u[t] = 0.f;
    if (t < OUT_SIZE) v[t] = 0.f;
    const float a = __logf((float)OUT_SIZE / (float)IN_SIZE);  // log(1/8)
    __syncthreads();

    for (int it = 0; it < MAX_ITER; ++it) {
        // ---- u update: thread t owns row i = t ----
        {
            const float* row = Kt + (long)t * 512;
            float mx = -INFINITY;
            #pragma unroll 8
            for (int s = 0; s < OUT_SIZE; s += 4) {
                const float4 kv = *(const float4*)(row + s);
                mx = fmaxf(mx, fmaxf(fmaxf(kv.x + v[s],     kv.y + v[s + 1]),
                                     fmaxf(kv.z + v[s + 2], kv.w + v[s + 3])));
            }
            float sum = 0.f;
            #pragma unroll 8
            for (int s = 0; s < OUT_SIZE; s += 4) {
                const float4 kv = *(const float4*)(row + s);
                sum += __expf(kv.x + v[s]     - mx) + __expf(kv.y + v[s + 1] - mx)
                     + __expf(kv.z + v[s + 2] - mx) + __expf(kv.w + v[s + 3] - mx);
            }
            const float unew = a - u[t] - (mx + __logf(sum));
            u[t] = unew;               // each thread touches only its own slot
        }
        __syncthreads();

        // ---- v update: s = t&127, r = t>>7 (8 threads per column) ----
        {
            const int s = t & 127, r = t >> 7;
            const float vold = v[s];
            float mx = -INFINITY;
            for (int i = r; i < IN_SIZE; i += 8)
                mx = fmaxf(mx, Kt[(long)i * 512 + s] + u[i]);
            red[t] = mx;
            __syncthreads();
            if (t < 512) red[t] = fmaxf(red[t], red[t + 512]);
            __syncthreads();
            if (t < 256) red[t] = fmaxf(red[t], red[t + 256]);
            __syncthreads();
            if (t < 128) red[t] = fmaxf(red[t], red[t + 128]);
            __syncthreads();
            const float cmx = red[s];
            __syncthreads();
            float sum = 0.f;
            for (int i = r; i < IN_SIZE; i += 8)
                sum += __expf(Kt[(long)i * 512 + s] + u[i] - cmx);
            red[t] = sum;
            __syncthreads();
            if (t < 512) red[t] += red[t + 512];
            __syncthreads();
            if (t < 256) red[t] += red[t + 256];
            __syncthreads();
            if (t < 128) red[t] += red[t + 128];
            __syncthreads();
            if (t < 128) v[t] = -vold - (cmx + __logf(red[t]));
            __syncthreads();
        }
    }

    // ---- T transposed write: Tt[b][s][i] = exp(K[i,s] + u[i] + v[s]) ----
    for (int idx = t; idx < IN_SIZE * OUT_SIZE; idx += 1024) {
        const int s = idx >> 10;       // idx / 1024
        const int i = idx & 1023;      // idx % 1024
        Tt[(long)b * (IN_SIZE * OUT_SIZE) + idx] =
            __expf(Kt[(long)i * 512 + s] + u[i] + v[s]);
    }
}

// ---------------------------------------------------------------------------
extern "C" void kernel_launch(void* const* d_in, const int* in_sizes, int n_in,
                              void* d_out, int out_size, void* d_ws, size_t ws_size,
                              hipStream_t stream)
{
    const float* x     = (const float*)d_in[0];   // [16][1024][1024]
    const float* otw   = (const float*)d_in[1];   // [4][128][1024] -> flat [512][1024]
    const float* lin_w = (const float*)d_in[2];   // [1024][4096]
    const float* lin_b = (const float*)d_in[3];   // [1024]
    float* out = (float*)d_out;                   // [16][128][1024]

    float* Kbuf = (float*)d_ws;                         // 16*1024*512 f32 = 32 MB
    float* Tt   = Kbuf + (long)NB * IN_SIZE * HEADS * OUT_SIZE;  // 64*128*1024 = 32 MB
    float* feat = Kbuf;                                 // reuse: K dead after sinkhorn

    // 1) K[n][i][m*128+s] = (x[n,i,:] . w[m,s,:]) / eps
    gemm_kernel<true, false><<<dim3(8, 16, NB), 256, 0, stream>>>(
        x, otw, nullptr, Kbuf, /*K=*/IN_DIM, /*lda=*/IN_DIM, /*ldb=*/IN_DIM,
        /*ldc=*/HEADS * OUT_SIZE,
        /*div=*/1, /*AsN=*/(long)IN_SIZE * IN_DIM, 0, 0, 0,
        /*CsN=*/(long)IN_SIZE * HEADS * OUT_SIZE, 0, 1.0f / EPSV);

    // 2) Sinkhorn -> Tt[b][s][i]
    sinkhorn_kernel<<<dim3(NB * HEADS), 1024, 0, stream>>>(Kbuf, Tt);

    // 3) feat[n][s][m*1024+d] = sum_i Tt[b][s][i] * x[n][i][d]
    gemm_kernel<false, false><<<dim3(16, 2, NB * HEADS), 256, 0, stream>>>(
        Tt, x, nullptr, feat, /*K=*/IN_SIZE, /*lda=*/IN_SIZE, /*ldb=*/IN_DIM,
        /*ldc=*/HEADS * IN_DIM,
        /*div=*/HEADS,
        /*AsN=*/(long)HEADS * OUT_SIZE * IN_SIZE, /*AsM=*/(long)OUT_SIZE * IN_SIZE,
        /*BsN=*/(long)IN_SIZE * IN_DIM, /*BsM=*/0,
        /*CsN=*/(long)OUT_SIZE * HEADS * IN_DIM, /*CsM=*/(long)IN_DIM, 1.0f);

    // 4) out[n][s][o] = relu(feat[n][s][:] . lin_w[o][:] + lin_b[o])
    gemm_kernel<true, true><<<dim3(16, 2, NB), 256, 0, stream>>>(
        feat, lin_w, lin_b, out, /*K=*/HEADS * IN_DIM, /*lda=*/HEADS * IN_DIM,
        /*ldb=*/HEADS * IN_DIM, /*ldc=*/OUT_DIM,
        /*div=*/1, /*AsN=*/(long)OUT_SIZE * HEADS * IN_DIM, 0, 0, 0,
        /*CsN=*/(long)OUT_SIZE * OUT_DIM, 0, 1.0f);
}

// Round 2
// 919.738 us; speedup vs baseline: 2.0041x; 2.0041x over previous
//
#include <hip/hip_runtime.h>
#include <math.h>

// Problem constants (from reference)
#define EPSV 0.1f
#define MAX_ITER 10
constexpr int NB       = 16;    // batch n
constexpr int IN_SIZE  = 1024;
constexpr int IN_DIM   = 1024;
constexpr int HEADS    = 4;
constexpr int OUT_SIZE = 128;
constexpr int OUT_DIM  = 1024;

// ---------------------------------------------------------------------------
// Generic fp32 64x64-tile GEMM: C = alpha * op(A) * op(B) (+bias, +relu)
// AT=true : A stored [K][M] row-major (k-major), C = A^T-view * op(B)
// BT=true : B stored [N][K] row-major (C = A * B^T), k-contiguous loads
// BT=false: B stored [K][N] row-major (C = A * B)
// Batched via blockIdx.z with offset = (bz/div)*sN + (bz%div)*sM per operand.
// ---------------------------------------------------------------------------
template<bool AT, bool BT, bool RELU>
__global__ __launch_bounds__(256)
void gemm_kernel(const float* __restrict__ A, const float* __restrict__ B,
                 const float* __restrict__ bias, float* __restrict__ C,
                 int K, int lda, int ldb, int ldc,
                 int div, long AsN, long AsM, long BsN, long BsM,
                 long CsN, long CsM, float alpha)
{
    const int bz = blockIdx.z;
    A += (long)(bz / div) * AsN + (long)(bz % div) * AsM;
    B += (long)(bz / div) * BsN + (long)(bz % div) * BsM;
    C += (long)(bz / div) * CsN + (long)(bz % div) * CsM;

    const int m0 = blockIdx.y * 64;
    const int n0 = blockIdx.x * 64;

    __shared__ float As[16][68];   // [k][m]
    __shared__ float Bs[16][68];   // [k][n]

    const int tid = threadIdx.x;
    const int tx = tid & 15;       // n micro
    const int ty = tid >> 4;       // m micro

    float acc[4][4] = {};

    for (int k0 = 0; k0 < K; k0 += 16) {
        // --- load A tile ---
        if (AT) {
            #pragma unroll
            for (int rep = 0; rep < 4; ++rep) {
                const int idx = rep * 256 + tid;
                const int kk = idx >> 6, mm = idx & 63;
                As[kk][mm] = A[(long)(k0 + kk) * lda + m0 + mm];
            }
        } else {
            const int r = tid >> 2;          // 0..63
            const int c = (tid & 3) * 4;     // 0,4,8,12
            const float4 av = *(const float4*)(A + (long)(m0 + r) * lda + k0 + c);
            As[c + 0][r] = av.x; As[c + 1][r] = av.y;
            As[c + 2][r] = av.z; As[c + 3][r] = av.w;
        }
        // --- load B tile ---
        if (BT) {
            const int r = tid >> 2;
            const int c = (tid & 3) * 4;
            const float4 bv = *(const float4*)(B + (long)(n0 + r) * ldb + k0 + c);
            Bs[c + 0][r] = bv.x; Bs[c + 1][r] = bv.y;
            Bs[c + 2][r] = bv.z; Bs[c + 3][r] = bv.w;
        } else {
            #pragma unroll
            for (int rep = 0; rep < 4; ++rep) {
                const int idx = rep * 256 + tid;
                const int kk = idx >> 6, nn = idx & 63;
                Bs[kk][nn] = B[(long)(k0 + kk) * ldb + n0 + nn];
            }
        }
        __syncthreads();

        #pragma unroll
        for (int kk = 0; kk < 16; ++kk) {
            const float4 a4 = *(const float4*)&As[kk][ty * 4];
            const float4 b4 = *(const float4*)&Bs[kk][tx * 4];
            const float a[4] = {a4.x, a4.y, a4.z, a4.w};
            const float b[4] = {b4.x, b4.y, b4.z, b4.w};
            #pragma unroll
            for (int i = 0; i < 4; ++i)
                #pragma unroll
                for (int j = 0; j < 4; ++j)
                    acc[i][j] = fmaf(a[i], b[j], acc[i][j]);
        }
        __syncthreads();
    }

    #pragma unroll
    for (int i = 0; i < 4; ++i) {
        const long m = m0 + ty * 4 + i;
        #pragma unroll
        for (int j = 0; j < 4; ++j) {
            const int n = n0 + tx * 4 + j;
            float val = acc[i][j] * alpha;
            if (RELU) { val += bias[n]; val = fmaxf(val, 0.f); }
            C[m * ldc + n] = val;
        }
    }
}

// ---------------------------------------------------------------------------
// Register-resident, exp-free log-Sinkhorn.
// One block (512 threads) per (n,m) tile, b = n*4+m.
// Thread (a = t>>3, c = t&7) owns rows a*16..a*16+15, cols c*16..c*16+15.
// Holds expKn = exp(K - rowmax) as 256 bf16 in 128 VGPRs.
//   u_new[i] = a0 - u_old[i] - (Mi + vmx + log(sum_s expKn*ev))
//   v_new[s] = -v_old[s] - (wmx + log(sum_i expKn*eu)),  w = Mi+u_new
// Mi cancels exactly vs the reference; all sum terms <= 1 (no overflow).
// Writes T row-major: Tb[b][i][s].
// ---------------------------------------------------------------------------
__global__ __launch_bounds__(512, 2)
void sinkhorn_kernel(const float* __restrict__ Kbuf, float* __restrict__ Tb)
{
    const int b = blockIdx.x;          // 0..63
    const int n = b >> 2, m = b & 3;
    const float* Kt = Kbuf + (long)n * IN_SIZE * 512 + m * OUT_SIZE; // row stride 512
    const int t = threadIdx.x;
    const int a = t >> 3;              // row-group 0..63
    const int c = t & 7;               // col-group 0..7
    const int lane = t & 63;
    const int wav  = t >> 6;           // 0..7

    __shared__ float Mi[1024];
    __shared__ float u_s[1024];
    __shared__ float w_s[1024];
    __shared__ float eu_s[1024];
    __shared__ float v_s[128];
    __shared__ float ev_s[128];
    __shared__ float redw[8][128];
    __shared__ float red8[8];

    // ---- pass 1: row maxes ----
    {
        float rmax[16];
        #pragma unroll
        for (int r = 0; r < 16; ++r) {
            const float* row = Kt + (long)(a * 16 + r) * 512 + c * 16;
            float kv[16];
            #pragma unroll
            for (int q = 0; q < 4; ++q) *(float4*)&kv[q * 4] = *(const float4*)(row + q * 4);
            float mx = kv[0];
            #pragma unroll
            for (int s = 1; s < 16; ++s) mx = fmaxf(mx, kv[s]);
            rmax[r] = mx;
        }
        #pragma unroll
        for (int msk = 1; msk <= 4; msk <<= 1)
            #pragma unroll
            for (int r = 0; r < 16; ++r)
                rmax[r] = fmaxf(rmax[r], __shfl_xor(rmax[r], msk, 64));
        if (c == 0) {
            #pragma unroll
            for (int r = 0; r < 16; ++r) Mi[a * 16 + r] = rmax[r];
        }
    }
    if (t < 128) v_s[t] = 0.f;
    u_s[t] = 0.f; u_s[t + 512] = 0.f;
    __syncthreads();

    // ---- pass 2: expKn -> bf16 regs (RNE pack) ----
    unsigned ek[16][8];
    #pragma unroll
    for (int r = 0; r < 16; ++r) {
        const float mi = Mi[a * 16 + r];
        const float* row = Kt + (long)(a * 16 + r) * 512 + c * 16;
        float kv[16];
        #pragma unroll
        for (int q = 0; q < 4; ++q) *(float4*)&kv[q * 4] = *(const float4*)(row + q * 4);
        #pragma unroll
        for (int j = 0; j < 8; ++j) {
            unsigned b0 = __float_as_uint(__expf(kv[2 * j]     - mi));
            unsigned b1 = __float_as_uint(__expf(kv[2 * j + 1] - mi));
            b0 = (b0 + 0x7fffu + ((b0 >> 16) & 1u)) >> 16;
            b1 = (b1 + 0x7fffu + ((b1 >> 16) & 1u)) & 0xffff0000u;
            ek[r][j] = b0 | b1;
        }
    }

    const float A0 = -2.0794415416798357f; // log(128/1024)
    float wmx = 0.f;

    for (int it = 0; it < MAX_ITER; ++it) {
        // ---- vmx + ev ----
        if (t < 128) {
            float xv = v_s[t];
            #pragma unroll
            for (int msk = 1; msk < 64; msk <<= 1) xv = fmaxf(xv, __shfl_xor(xv, msk, 64));
            if (lane == 0) red8[wav] = xv;
        }
        __syncthreads();
        const float vmx = fmaxf(red8[0], red8[1]);
        if (t < 128) ev_s[t] = __expf(v_s[t] - vmx);
        __syncthreads();

        // ---- u-pass: row sums of expKn * ev ----
        float evr[16];
        #pragma unroll
        for (int q = 0; q < 4; ++q) *(float4*)&evr[q * 4] = *(const float4*)&ev_s[c * 16 + q * 4];
        float part[16];
        #pragma unroll
        for (int r = 0; r < 16; ++r) part[r] = 0.f;
        #pragma unroll
        for (int j = 0; j < 8; ++j) {
            const float e0 = evr[2 * j], e1 = evr[2 * j + 1];
            #pragma unroll
            for (int r = 0; r < 16; ++r)
                part[r] = fmaf(__uint_as_float(ek[r][j] << 16), e0, part[r]);
            #pragma unroll
            for (int r = 0; r < 16; ++r)
                part[r] = fmaf(__uint_as_float(ek[r][j] & 0xffff0000u), e1, part[r]);
        }
        #pragma unroll
        for (int msk = 1; msk <= 4; msk <<= 1)
            #pragma unroll
            for (int r = 0; r < 16; ++r) part[r] += __shfl_xor(part[r], msk, 64);

        float wloc = -INFINITY;
        if (c == 0) {
            #pragma unroll
            for (int r = 0; r < 16; ++r) {
                const int row = a * 16 + r;
                const float un = A0 - u_s[row] - Mi[row] - vmx - __logf(part[r]);
                u_s[row] = un;
                const float wv = Mi[row] + un;
                w_s[row] = wv;
                wloc = fmaxf(wloc, wv);
            }
        }
        #pragma unroll
        for (int msk = 1; msk < 64; msk <<= 1) wloc = fmaxf(wloc, __shfl_xor(wloc, msk, 64));
        if (lane == 0) red8[wav] = wloc;
        __syncthreads();
        wmx = red8[0];
        #pragma unroll
        for (int q = 1; q < 8; ++q) wmx = fmaxf(wmx, red8[q]);
        eu_s[t]       = __expf(w_s[t]       - wmx);
        eu_s[t + 512] = __expf(w_s[t + 512] - wmx);
        __syncthreads();

        // ---- v-pass: col sums of expKn * eu ----
        float eur[16];
        #pragma unroll
        for (int q = 0; q < 4; ++q) *(float4*)&eur[q * 4] = *(const float4*)&eu_s[a * 16 + q * 4];
        float cpart[16];
        #pragma unroll
        for (int s = 0; s < 16; ++s) cpart[s] = 0.f;
        #pragma unroll
        for (int r = 0; r < 16; ++r) {
            const float er = eur[r];
            #pragma unroll
            for (int j = 0; j < 8; ++j) {
                cpart[2 * j]     = fmaf(__uint_as_float(ek[r][j] << 16),        er, cpart[2 * j]);
                cpart[2 * j + 1] = fmaf(__uint_as_float(ek[r][j] & 0xffff0000u), er, cpart[2 * j + 1]);
            }
        }
        #pragma unroll
        for (int msk = 8; msk <= 32; msk <<= 1)
            #pragma unroll
            for (int s = 0; s < 16; ++s) cpart[s] += __shfl_xor(cpart[s], msk, 64);
        if (lane < 8) {   // lane == c for the a&7==0 row-group
            #pragma unroll
            for (int s = 0; s < 16; ++s) redw[wav][c * 16 + s] = cpart[s];
        }
        __syncthreads();
        if (t < 128) {
            float ssum = redw[0][t];
            #pragma unroll
            for (int q = 1; q < 8; ++q) ssum += redw[q][t];
            v_s[t] = -v_s[t] - wmx - __logf(ssum);
        }
        __syncthreads();
    }

    // ---- final T = expKn * exp(Mi + u + v), row-major coalesced ----
    float vfin[16];
    #pragma unroll
    for (int q = 0; q < 4; ++q) *(float4*)&vfin[q * 4] = *(const float4*)&v_s[c * 16 + q * 4];
    float* To = Tb + (long)b * (IN_SIZE * OUT_SIZE);
    #pragma unroll
    for (int r = 0; r < 16; ++r) {
        const int row = a * 16 + r;
        const float muw = Mi[row] + u_s[row];
        float outv[16];
        #pragma unroll
        for (int j = 0; j < 8; ++j) {
            outv[2 * j]     = __uint_as_float(ek[r][j] << 16)         * __expf(muw + vfin[2 * j]);
            outv[2 * j + 1] = __uint_as_float(ek[r][j] & 0xffff0000u) * __expf(muw + vfin[2 * j + 1]);
        }
        #pragma unroll
        for (int q = 0; q < 4; ++q)
            *(float4*)(To + (long)row * 128 + c * 16 + q * 4) = *(float4*)&outv[q * 4];
    }
}

// ---------------------------------------------------------------------------
extern "C" void kernel_launch(void* const* d_in, const int* in_sizes, int n_in,
                              void* d_out, int out_size, void* d_ws, size_t ws_size,
                              hipStream_t stream)
{
    const float* x     = (const float*)d_in[0];   // [16][1024][1024]
    const float* otw   = (const float*)d_in[1];   // [4][128][1024] -> flat [512][1024]
    const float* lin_w = (const float*)d_in[2];   // [1024][4096]
    const float* lin_b = (const float*)d_in[3];   // [1024]
    float* out = (float*)d_out;                   // [16][128][1024]

    float* Kbuf = (float*)d_ws;                                      // 32 MB
    float* Tb   = Kbuf + (long)NB * IN_SIZE * HEADS * OUT_SIZE;      // 32 MB
    float* feat = Kbuf;                                              // reuse

    // 1) K[n][i][m*128+s] = (x[n,i,:] . w[m,s,:]) / eps
    gemm_kernel<false, true, false><<<dim3(8, 16, NB), 256, 0, stream>>>(
        x, otw, nullptr, Kbuf, IN_DIM, IN_DIM, IN_DIM, HEADS * OUT_SIZE,
        1, (long)IN_SIZE * IN_DIM, 0, 0, 0,
        (long)IN_SIZE * HEADS * OUT_SIZE, 0, 1.0f / EPSV);

    // 2) Sinkhorn -> Tb[b][i][s] (row-major)
    sinkhorn_kernel<<<dim3(NB * HEADS), 512, 0, stream>>>(Kbuf, Tb);

    // 3) feat[n][s][m*1024+d] = sum_i Tb[b][i][s] * x[n][i][d]  (A k-major)
    gemm_kernel<true, false, false><<<dim3(16, 2, NB * HEADS), 256, 0, stream>>>(
        Tb, x, nullptr, feat, IN_SIZE, /*lda=*/OUT_SIZE, IN_DIM, HEADS * IN_DIM,
        HEADS,
        (long)HEADS * IN_SIZE * OUT_SIZE, (long)IN_SIZE * OUT_SIZE,
        (long)IN_SIZE * IN_DIM, 0,
        (long)OUT_SIZE * HEADS * IN_DIM, (long)IN_DIM, 1.0f);

    // 4) out[n][s][o] = relu(feat[n][s][:] . lin_w[o][:] + lin_b[o])
    gemm_kernel<false, true, true><<<dim3(16, 2, NB), 256, 0, stream>>>(
        feat, lin_w, lin_b, out, HEADS * IN_DIM, HEADS * IN_DIM,
        HEADS * IN_DIM, OUT_DIM,
        1, (long)OUT_SIZE * HEADS * IN_DIM, 0, 0, 0,
        (long)OUT_SIZE * OUT_DIM, 0, 1.0f);
}

// Round 4
// 362.692 us; speedup vs baseline: 5.0821x; 2.5359x over previous
//
#include <hip/hip_runtime.h>
#include <math.h>

#define EPSV 0.1f
#define MAX_ITER 10
constexpr int NB       = 16;
constexpr int IN_SIZE  = 1024;
constexpr int IN_DIM   = 1024;
constexpr int HEADS    = 4;
constexpr int OUT_SIZE = 128;
constexpr int OUT_DIM  = 1024;

typedef __attribute__((ext_vector_type(8))) _Float16 f16x8;
typedef __attribute__((ext_vector_type(4))) float f32x4;

// fp32 -> fp16 RNE (v_cvt_f16_f32 default round mode), packed pair
__device__ __forceinline__ unsigned cvth2(float lo, float hi) {
    _Float16 a = (_Float16)lo, b = (_Float16)hi;
    unsigned short ua = *(unsigned short*)&a, ub = *(unsigned short*)&b;
    return (unsigned)ua | ((unsigned)ub << 16);
}
__device__ __forceinline__ unsigned short cvth1(float f) {
    _Float16 a = (_Float16)f;
    return *(unsigned short*)&a;
}
// fp32 -> bf16 RNE (bit trick; used only inside sinkhorn for ek)
__device__ __forceinline__ unsigned rne2(float lo, float hi) {
    unsigned a = __float_as_uint(lo), b = __float_as_uint(hi);
    a = (a + 0x7fffu + ((a >> 16) & 1u)) >> 16;
    b = (b + 0x7fffu + ((b >> 16) & 1u)) & 0xffff0000u;
    return a | b;
}

// ---------------------------------------------------------------------------
// MFMA fp16 GEMM, M fixed at 128. C = alpha*A*B^T (+bias,+relu).
// A[128][K], B[N][K] both k-major. fp32 sources are converted to fp16 (RNE)
// during reg-staging. LDS rows padded to 40 f16 (80 B = 5x16B) -> 2-way-only
// bank aliasing on ds_read_b128 fragment loads.
// AKBLK: A's K axis is blocked as (k>>10) blocks of stride AkStride elems.
// ---------------------------------------------------------------------------
template<bool A_F32, bool B_F32, bool C_F16, bool RELU, int NF, bool AKBLK>
__global__ __launch_bounds__(256)
void mfma_gemm(const void* __restrict__ Ap, const void* __restrict__ Bp,
               const float* __restrict__ bias, void* __restrict__ Cp,
               int K, int lda, int ldb, int ldc, int div,
               long AsN, long AsM, long BsN, long BsM, long CsN, long CsM,
               long AkStride, float alpha)
{
    constexpr int BN  = NF * 32;
    constexpr int BKP = 40;            // padded LDS row stride (f16 elems)
    const int z = blockIdx.z;
    const long aoff = (long)(z / div) * AsN + (long)(z % div) * AsM;
    const long boff = (long)(z / div) * BsN + (long)(z % div) * BsM;
    const long coff = (long)(z / div) * CsN + (long)(z % div) * CsM;
    const int n0 = blockIdx.x * BN;

    __shared__ short As[128 * BKP];
    __shared__ short Bs[BN * BKP];

    const int t = threadIdx.x;
    const int lane = t & 63;
    const int w = t >> 6, wr = w >> 1, wc = w & 1;

    f32x4 acc[4][NF];
    #pragma unroll
    for (int i = 0; i < 4; ++i)
        #pragma unroll
        for (int j = 0; j < NF; ++j) { acc[i][j].x = 0.f; acc[i][j].y = 0.f; acc[i][j].z = 0.f; acc[i][j].w = 0.f; }

    for (int k0 = 0; k0 < K; k0 += 32) {
        const long abase = AKBLK ? aoff + (long)(k0 >> 10) * AkStride + (k0 & 1023)
                                 : aoff + k0;
        const long bbase = boff + k0;
        // ---- stage A (128 x 32) ----
        #pragma unroll
        for (int itr = 0; itr < 2; ++itr) {
            const int idx = itr * 256 + t;
            const int row = idx >> 2, kq = idx & 3;
            uint4 p;
            if (A_F32) {
                const float* s = (const float*)Ap + abase + (long)row * lda + kq * 8;
                const float4 f0 = *(const float4*)s, f1 = *(const float4*)(s + 4);
                p.x = cvth2(f0.x, f0.y); p.y = cvth2(f0.z, f0.w);
                p.z = cvth2(f1.x, f1.y); p.w = cvth2(f1.z, f1.w);
            } else {
                p = *(const uint4*)((const short*)Ap + abase + (long)row * lda + kq * 8);
            }
            *(uint4*)&As[row * BKP + kq * 8] = p;
        }
        // ---- stage B (BN x 32) ----
        #pragma unroll
        for (int itr = 0; itr < BN / 64; ++itr) {
            const int idx = itr * 256 + t;
            const int row = idx >> 2, kq = idx & 3;
            uint4 p;
            if (B_F32) {
                const float* s = (const float*)Bp + bbase + (long)(n0 + row) * ldb + kq * 8;
                const float4 f0 = *(const float4*)s, f1 = *(const float4*)(s + 4);
                p.x = cvth2(f0.x, f0.y); p.y = cvth2(f0.z, f0.w);
                p.z = cvth2(f1.x, f1.y); p.w = cvth2(f1.z, f1.w);
            } else {
                p = *(const uint4*)((const short*)Bp + bbase + (long)(n0 + row) * ldb + kq * 8);
            }
            *(uint4*)&Bs[row * BKP + kq * 8] = p;
        }
        __syncthreads();

        f16x8 af[4], bfr[NF];
        #pragma unroll
        for (int mi = 0; mi < 4; ++mi)
            af[mi] = *(const f16x8*)&As[(wr * 64 + mi * 16 + (lane & 15)) * BKP + (lane >> 4) * 8];
        #pragma unroll
        for (int ni = 0; ni < NF; ++ni)
            bfr[ni] = *(const f16x8*)&Bs[(wc * (BN / 2) + ni * 16 + (lane & 15)) * BKP + (lane >> 4) * 8];
        #pragma unroll
        for (int mi = 0; mi < 4; ++mi)
            #pragma unroll
            for (int ni = 0; ni < NF; ++ni)
                acc[mi][ni] = __builtin_amdgcn_mfma_f32_16x16x32_f16(af[mi], bfr[ni], acc[mi][ni], 0, 0, 0);
        __syncthreads();
    }

    #pragma unroll
    for (int mi = 0; mi < 4; ++mi) {
        #pragma unroll
        for (int ni = 0; ni < NF; ++ni) {
            #pragma unroll
            for (int j = 0; j < 4; ++j) {
                const int row = wr * 64 + mi * 16 + (lane >> 4) * 4 + j;
                const int col = n0 + wc * (BN / 2) + ni * 16 + (lane & 15);
                float v = acc[mi][ni][j] * alpha;
                if (RELU) { v += bias[col]; v = fmaxf(v, 0.f); }
                if (C_F16) ((unsigned short*)Cp)[coff + (long)row * ldc + col] = cvth1(v);
                else       ((float*)Cp)[coff + (long)row * ldc + col] = v;
            }
        }
    }
}

// ---------------------------------------------------------------------------
// x [n][i][d] fp32 -> xT [n][d][i] fp16 (RNE), 64x64 LDS tiles.
// ---------------------------------------------------------------------------
__global__ __launch_bounds__(256)
void transpose_cvt(const float* __restrict__ x, unsigned short* __restrict__ xT)
{
    const int n = blockIdx.z, i0 = blockIdx.y * 64, d0 = blockIdx.x * 64;
    const float* xs = x + (long)n * (IN_SIZE * IN_DIM);
    unsigned short* xo = xT + (long)n * (IN_SIZE * IN_DIM);
    __shared__ float tile[64][65];
    const int t = threadIdx.x;
    const int r = t >> 4, c4 = (t & 15) * 4;
    #pragma unroll
    for (int rr = 0; rr < 4; ++rr) {
        const float4 v = *(const float4*)(xs + (long)(i0 + rr * 16 + r) * IN_DIM + d0 + c4);
        *(float4*)&tile[rr * 16 + r][c4] = v;
    }
    __syncthreads();
    #pragma unroll
    for (int rr = 0; rr < 4; ++rr) {
        const int dl = rr * 16 + r;
        ushort4 o;
        o.x = cvth1(tile[c4 + 0][dl]); o.y = cvth1(tile[c4 + 1][dl]);
        o.z = cvth1(tile[c4 + 2][dl]); o.w = cvth1(tile[c4 + 3][dl]);
        *(ushort4*)(xo + (long)(d0 + dl) * IN_SIZE + i0 + c4) = o;
    }
}

// ---------------------------------------------------------------------------
// Sinkhorn on Kt[b][s=128][i=1024] fp32 (row stride 1024), 512 threads/tile.
// Wave w (of 8) owns s rows w*16..w*16+15; lane covers i = q*256+lane*4+e, so
// every wave's lanes span ALL 1024 i -> v-pass i-reduce is one in-wave
// butterfly. ek = bf16(exp(K - Mi)) lives in 128 VGPRs (bit-shift unpack).
// Writes Tt fp16 over the first half of its own (dead) K tile.
// ---------------------------------------------------------------------------
__global__ __launch_bounds__(512)
void sinkhorn_t(float* base)
{
    const int b = blockIdx.x;
    float* Kt = base + (long)b * (OUT_SIZE * IN_SIZE);     // [128][1024]
    unsigned short* Tt = (unsigned short*)Kt;              // fp16 overlay
    const int t = threadIdx.x;
    const int lane = t & 63, w = t >> 6;

    __shared__ float part[8][1024];
    __shared__ float Mi[1024], eu_s[1024];
    __shared__ float v_s[128], ev_s[128];
    __shared__ float red8[8], red2[2];

    // ---- pass A: Mi[i] = max_s K[s][i] ----
    {
        f32x4 pm[4];
        #pragma unroll
        for (int q = 0; q < 4; ++q) { pm[q].x = -INFINITY; pm[q].y = -INFINITY; pm[q].z = -INFINITY; pm[q].w = -INFINITY; }
        for (int r = 0; r < 16; ++r) {
            const float* rowp = Kt + (long)(w * 16 + r) * 1024 + lane * 4;
            #pragma unroll
            for (int q = 0; q < 4; ++q) {
                const float4 kv = *(const float4*)(rowp + q * 256);
                pm[q].x = fmaxf(pm[q].x, kv.x); pm[q].y = fmaxf(pm[q].y, kv.y);
                pm[q].z = fmaxf(pm[q].z, kv.z); pm[q].w = fmaxf(pm[q].w, kv.w);
            }
        }
        #pragma unroll
        for (int q = 0; q < 4; ++q) *(f32x4*)&part[w][q * 256 + lane * 4] = pm[q];
    }
    if (t < 128) v_s[t] = 0.f;
    __syncthreads();
    #pragma unroll
    for (int h = 0; h < 2; ++h) {
        const int i = t + h * 512;
        float mx = part[0][i];
        #pragma unroll
        for (int q = 1; q < 8; ++q) mx = fmaxf(mx, part[q][i]);
        Mi[i] = mx;
    }
    __syncthreads();

    // ---- pass B: ek = bf16(exp(K - Mi)) ----
    f32x4 mi4[4];
    #pragma unroll
    for (int q = 0; q < 4; ++q) mi4[q] = *(f32x4*)&Mi[q * 256 + lane * 4];
    unsigned ek[16][8];
    for (int r = 0; r < 16; ++r) {
        const float* rowp = Kt + (long)(w * 16 + r) * 1024 + lane * 4;
        #pragma unroll
        for (int q = 0; q < 4; ++q) {
            const float4 kv = *(const float4*)(rowp + q * 256);
            ek[r][2 * q]     = rne2(__expf(kv.x - mi4[q].x), __expf(kv.y - mi4[q].y));
            ek[r][2 * q + 1] = rne2(__expf(kv.z - mi4[q].z), __expf(kv.w - mi4[q].w));
        }
    }

    const float A0 = -2.0794415416798357f;   // log(128/1024)
    float u_reg[2] = {0.f, 0.f};
    float wmx = 0.f;

    for (int it = 0; it < MAX_ITER; ++it) {
        // ---- vmx + ev ----
        if (t < 128) {
            float xv = v_s[t];
            #pragma unroll
            for (int m = 1; m < 64; m <<= 1) xv = fmaxf(xv, __shfl_xor(xv, m, 64));
            if (lane == 0) red2[w] = xv;
        }
        __syncthreads();
        const float vmx = fmaxf(red2[0], red2[1]);
        if (t < 128) ev_s[t] = __expf(v_s[t] - vmx);
        __syncthreads();

        // ---- u-pass: S[i] = sum_s ek*ev ----
        {
            f32x4 a4[4];
            #pragma unroll
            for (int q = 0; q < 4; ++q) { a4[q].x = 0.f; a4[q].y = 0.f; a4[q].z = 0.f; a4[q].w = 0.f; }
            #pragma unroll
            for (int r = 0; r < 16; ++r) {
                const float evv = ev_s[w * 16 + r];
                #pragma unroll
                for (int q = 0; q < 4; ++q) {
                    const unsigned e0 = ek[r][2 * q], e1 = ek[r][2 * q + 1];
                    a4[q].x = fmaf(__uint_as_float(e0 << 16),          evv, a4[q].x);
                    a4[q].y = fmaf(__uint_as_float(e0 & 0xffff0000u),  evv, a4[q].y);
                    a4[q].z = fmaf(__uint_as_float(e1 << 16),          evv, a4[q].z);
                    a4[q].w = fmaf(__uint_as_float(e1 & 0xffff0000u),  evv, a4[q].w);
                }
            }
            #pragma unroll
            for (int q = 0; q < 4; ++q) *(f32x4*)&part[w][q * 256 + lane * 4] = a4[q];
        }
        __syncthreads();
        {
            float wloc = -INFINITY, wv[2];
            #pragma unroll
            for (int h = 0; h < 2; ++h) {
                const int i = t + h * 512;
                float S = part[0][i];
                #pragma unroll
                for (int q = 1; q < 8; ++q) S += part[q][i];
                const float un = A0 - u_reg[h] - Mi[i] - vmx - __logf(S);
                u_reg[h] = un;
                wv[h] = Mi[i] + un;
                wloc = fmaxf(wloc, wv[h]);
            }
            #pragma unroll
            for (int m = 1; m < 64; m <<= 1) wloc = fmaxf(wloc, __shfl_xor(wloc, m, 64));
            if (lane == 0) red8[w] = wloc;
            __syncthreads();
            wmx = red8[0];
            #pragma unroll
            for (int q = 1; q < 8; ++q) wmx = fmaxf(wmx, red8[q]);
            eu_s[t]       = __expf(wv[0] - wmx);
            eu_s[t + 512] = __expf(wv[1] - wmx);
        }
        __syncthreads();

        // ---- v-pass: sum_i ek*eu, full in-wave i-butterfly ----
        {
            f32x4 eur[4];
            #pragma unroll
            for (int q = 0; q < 4; ++q) eur[q] = *(f32x4*)&eu_s[q * 256 + lane * 4];
            float cp[16];
            #pragma unroll
            for (int r = 0; r < 16; ++r) {
                float s0 = 0.f;
                #pragma unroll
                for (int q = 0; q < 4; ++q) {
                    const unsigned e0 = ek[r][2 * q], e1 = ek[r][2 * q + 1];
                    s0 = fmaf(__uint_as_float(e0 << 16),         eur[q].x, s0);
                    s0 = fmaf(__uint_as_float(e0 & 0xffff0000u), eur[q].y, s0);
                    s0 = fmaf(__uint_as_float(e1 << 16),         eur[q].z, s0);
                    s0 = fmaf(__uint_as_float(e1 & 0xffff0000u), eur[q].w, s0);
                }
                cp[r] = s0;
            }
            #pragma unroll
            for (int m = 1; m < 64; m <<= 1)
                #pragma unroll
                for (int r = 0; r < 16; ++r) cp[r] += __shfl_xor(cp[r], m, 64);
            if (lane == 0) {
                #pragma unroll
                for (int r = 0; r < 16; ++r)
                    v_s[w * 16 + r] = -v_s[w * 16 + r] - wmx - __logf(cp[r]);
            }
        }
        __syncthreads();
    }

    // ---- T[s][i] = ek * eu[i] * exp(wmx + v[s]) -> fp16, overlay write ----
    f32x4 eur[4];
    #pragma unroll
    for (int q = 0; q < 4; ++q) eur[q] = *(f32x4*)&eu_s[q * 256 + lane * 4];
    for (int r = 0; r < 16; ++r) {
        const int sr = w * 16 + r;
        const float ec = __expf(v_s[sr] + wmx);
        #pragma unroll
        for (int q = 0; q < 4; ++q) {
            const unsigned e0 = ek[r][2 * q], e1 = ek[r][2 * q + 1];
            ushort4 o;
            o.x = cvth1(__uint_as_float(e0 << 16)         * eur[q].x * ec);
            o.y = cvth1(__uint_as_float(e0 & 0xffff0000u) * eur[q].y * ec);
            o.z = cvth1(__uint_as_float(e1 << 16)         * eur[q].z * ec);
            o.w = cvth1(__uint_as_float(e1 & 0xffff0000u) * eur[q].w * ec);
            *(ushort4*)(Tt + (long)sr * 1024 + q * 256 + lane * 4) = o;
        }
    }
}

// ---------------------------------------------------------------------------
extern "C" void kernel_launch(void* const* d_in, const int* in_sizes, int n_in,
                              void* d_out, int out_size, void* d_ws, size_t ws_size,
                              hipStream_t stream)
{
    const float* x     = (const float*)d_in[0];   // [16][1024][1024]
    const float* otw   = (const float*)d_in[1];   // [4][128][1024]
    const float* lin_w = (const float*)d_in[2];   // [1024][4096]
    const float* lin_b = (const float*)d_in[3];   // [1024]
    float* out = (float*)d_out;                   // [16][128][1024] fp32

    // ws (64 MB): [0,32M) xT fp16 [16][1024][1024]
    //             [32M,64M) 64 tiles x 512KB: Kt fp32 [128][1024]
    //               after sinkhorn: first 256KB = Tt fp16, second 256KB = feat fp16
    unsigned short* xT = (unsigned short*)d_ws;
    float* Kt = (float*)d_ws + 8388608;
    unsigned short* TtBase   = (unsigned short*)Kt;
    unsigned short* featBase = TtBase + 131072;

    // 0) x -> xT fp16
    transpose_cvt<<<dim3(16, 16, NB), 256, 0, stream>>>(x, xT);

    // 1) Kt[b=(n,m)][s][i] = 10 * sum_d otw[m,s,d]*x[n,i,d]
    mfma_gemm<true, true, false, false, 4, false><<<dim3(8, 1, 64), 256, 0, stream>>>(
        otw, x, nullptr, Kt, 1024, 1024, 1024, 1024, 4,
        0, 131072, 1048576, 0, 524288, 131072, 0, 1.0f / EPSV);

    // 2) Sinkhorn -> Tt fp16 (overlay)
    sinkhorn_t<<<dim3(64), 512, 0, stream>>>(Kt);

    // 3) feat[b][s][d] = sum_i Tt[b][s][i]*xT[n][d][i] -> fp16 holes
    mfma_gemm<false, false, true, false, 4, false><<<dim3(8, 1, 64), 256, 0, stream>>>(
        TtBase, xT, nullptr, featBase, 1024, 1024, 1024, 1024, 4,
        1048576, 262144, 1048576, 0, 1048576, 262144, 0, 1.0f);

    // 4) out[n][s][o] = relu(sum_{m,d} feat * lin_w[o][m*1024+d] + b[o])
    mfma_gemm<false, true, false, true, 2, true><<<dim3(16, 1, NB), 256, 0, stream>>>(
        featBase, lin_w, lin_b, out, 4096, 1024, 4096, 1024, 1,
        1048576, 0, 0, 0, 131072, 0, 262144, 1.0f);
}

// Round 5
// 312.116 us; speedup vs baseline: 5.9057x; 1.1620x over previous
//
#include <hip/hip_runtime.h>
#include <math.h>

#define EPSV 0.1f
#define MAX_ITER 10
constexpr int NB       = 16;
constexpr int IN_SIZE  = 1024;
constexpr int IN_DIM   = 1024;
constexpr int HEADS    = 4;
constexpr int OUT_SIZE = 128;
constexpr int OUT_DIM  = 1024;

typedef __attribute__((ext_vector_type(8))) _Float16 f16x8;
typedef __attribute__((ext_vector_type(4))) float f32x4;

// fp32 -> fp16 RNE, packed pair
__device__ __forceinline__ unsigned cvth2(float lo, float hi) {
    _Float16 a = (_Float16)lo, b = (_Float16)hi;
    unsigned short ua = *(unsigned short*)&a, ub = *(unsigned short*)&b;
    return (unsigned)ua | ((unsigned)ub << 16);
}
__device__ __forceinline__ unsigned short cvth1(float f) {
    _Float16 a = (_Float16)f;
    return *(unsigned short*)&a;
}
// fp32 -> bf16 RNE single
__device__ __forceinline__ unsigned short bf16rne(float f) {
    unsigned a = __float_as_uint(f);
    return (unsigned short)((a + 0x7fffu + ((a >> 16) & 1u)) >> 16);
}

// ---------------------------------------------------------------------------
// MFMA fp16 GEMM, M fixed at 128. C = alpha*A*B^T (+variants).
// AMODE: 0 = A fp16 passthrough, 2 = A bf16-ek scaled by eu[i] during staging
// B_F32: B fp32 -> fp16 in-flight, else fp16 passthrough
// CMODE: 1 = fp16 store, 2 = f32 + bias + relu, 3 = fp16 * ecv[row]
// AKBLK: A's K axis blocked as (k>>10) blocks of stride AkStride elems.
// ---------------------------------------------------------------------------
template<int AMODE, bool B_F32, int CMODE, int NF, bool AKBLK>
__global__ __launch_bounds__(256)
void mfma_gemm(const void* __restrict__ Ap, const void* __restrict__ Bp,
               const float* __restrict__ bias, void* __restrict__ Cp,
               const float* __restrict__ euv,
               int K, int lda, int ldb, int ldc, int div,
               long AsN, long AsM, long BsN, long BsM, long CsN, long CsM,
               long AkStride, float alpha)
{
    constexpr int BN  = NF * 32;
    constexpr int BKP = 40;            // padded LDS row stride (f16 elems)
    const int z = blockIdx.z;
    const long aoff = (long)(z / div) * AsN + (long)(z % div) * AsM;
    const long boff = (long)(z / div) * BsN + (long)(z % div) * BsM;
    const long coff = (long)(z / div) * CsN + (long)(z % div) * CsM;
    const int n0 = blockIdx.x * BN;

    __shared__ short As[128 * BKP];
    __shared__ short Bs[BN * BKP];
    __shared__ float ecv_s[128];

    const int t = threadIdx.x;
    const int lane = t & 63;
    const int w = t >> 6, wr = w >> 1, wc = w & 1;

    if (CMODE == 3 && t < 128) ecv_s[t] = euv[(long)z * 1152 + 1024 + t];

    f32x4 acc[4][NF];
    #pragma unroll
    for (int i = 0; i < 4; ++i)
        #pragma unroll
        for (int j = 0; j < NF; ++j) { acc[i][j].x = 0.f; acc[i][j].y = 0.f; acc[i][j].z = 0.f; acc[i][j].w = 0.f; }

    for (int k0 = 0; k0 < K; k0 += 32) {
        const long abase = AKBLK ? aoff + (long)(k0 >> 10) * AkStride + (k0 & 1023)
                                 : aoff + k0;
        const long bbase = boff + k0;
        // ---- stage A (128 x 32) ----
        #pragma unroll
        for (int itr = 0; itr < 2; ++itr) {
            const int idx = itr * 256 + t;
            const int row = idx >> 2, kq = idx & 3;
            uint4 p;
            if (AMODE == 2) {
                const uint4 e = *(const uint4*)((const short*)Ap + abase + (long)row * lda + kq * 8);
                const float* eup = euv + (long)z * 1152 + k0 + kq * 8;
                const float4 e0 = *(const float4*)eup, e1 = *(const float4*)(eup + 4);
                p.x = cvth2(__uint_as_float(e.x << 16) * e0.x, __uint_as_float(e.x & 0xffff0000u) * e0.y);
                p.y = cvth2(__uint_as_float(e.y << 16) * e0.z, __uint_as_float(e.y & 0xffff0000u) * e0.w);
                p.z = cvth2(__uint_as_float(e.z << 16) * e1.x, __uint_as_float(e.z & 0xffff0000u) * e1.y);
                p.w = cvth2(__uint_as_float(e.w << 16) * e1.z, __uint_as_float(e.w & 0xffff0000u) * e1.w);
            } else {
                p = *(const uint4*)((const short*)Ap + abase + (long)row * lda + kq * 8);
            }
            *(uint4*)&As[row * BKP + kq * 8] = p;
        }
        // ---- stage B (BN x 32) ----
        #pragma unroll
        for (int itr = 0; itr < BN / 64; ++itr) {
            const int idx = itr * 256 + t;
            const int row = idx >> 2, kq = idx & 3;
            uint4 p;
            if (B_F32) {
                const float* s = (const float*)Bp + bbase + (long)(n0 + row) * ldb + kq * 8;
                const float4 f0 = *(const float4*)s, f1 = *(const float4*)(s + 4);
                p.x = cvth2(f0.x, f0.y); p.y = cvth2(f0.z, f0.w);
                p.z = cvth2(f1.x, f1.y); p.w = cvth2(f1.z, f1.w);
            } else {
                p = *(const uint4*)((const short*)Bp + bbase + (long)(n0 + row) * ldb + kq * 8);
            }
            *(uint4*)&Bs[row * BKP + kq * 8] = p;
        }
        __syncthreads();

        f16x8 af[4], bfr[NF];
        #pragma unroll
        for (int mi = 0; mi < 4; ++mi)
            af[mi] = *(const f16x8*)&As[(wr * 64 + mi * 16 + (lane & 15)) * BKP + (lane >> 4) * 8];
        #pragma unroll
        for (int ni = 0; ni < NF; ++ni)
            bfr[ni] = *(const f16x8*)&Bs[(wc * (BN / 2) + ni * 16 + (lane & 15)) * BKP + (lane >> 4) * 8];
        #pragma unroll
        for (int mi = 0; mi < 4; ++mi)
            #pragma unroll
            for (int ni = 0; ni < NF; ++ni)
                acc[mi][ni] = __builtin_amdgcn_mfma_f32_16x16x32_f16(af[mi], bfr[ni], acc[mi][ni], 0, 0, 0);
        __syncthreads();
    }

    #pragma unroll
    for (int mi = 0; mi < 4; ++mi) {
        #pragma unroll
        for (int ni = 0; ni < NF; ++ni) {
            #pragma unroll
            for (int j = 0; j < 4; ++j) {
                const int row = wr * 64 + mi * 16 + (lane >> 4) * 4 + j;
                const int col = n0 + wc * (BN / 2) + ni * 16 + (lane & 15);
                float v = acc[mi][ni][j] * alpha;
                if (CMODE == 2) { v += bias[col]; v = fmaxf(v, 0.f); }
                if (CMODE == 3) v *= ecv_s[row];
                if (CMODE == 2) ((float*)Cp)[coff + (long)row * ldc + col] = v;
                else            ((unsigned short*)Cp)[coff + (long)row * ldc + col] = cvth1(v);
            }
        }
    }
}

// ---------------------------------------------------------------------------
// GEMM1 fused: K = 10 * otw[m] . x[n]^T for one (b, i-chunk); computes
// Mi[i] = max_s K (block holds ALL 128 s), writes ek = bf16(exp(K - Mi))
// and Mi. One block per (i-chunk 128, b).
// ---------------------------------------------------------------------------
__global__ __launch_bounds__(256)
void gemm1_exp(const float* __restrict__ otw, const float* __restrict__ x,
               unsigned short* __restrict__ ekb, float* __restrict__ MiB)
{
    constexpr int BKP = 40;
    const int z = blockIdx.z;                 // b = n*4+m
    const int nn = z >> 2, mm = z & 3;
    const float* A = otw + (long)mm * (OUT_SIZE * IN_DIM);   // [128][1024]
    const float* B = x   + (long)nn * (IN_SIZE * IN_DIM);    // [1024][1024]
    const int n0 = blockIdx.x * 128;          // i-chunk

    __shared__ short As[128 * BKP];
    __shared__ short Bs[128 * BKP];
    __shared__ float colmax[2][128];

    const int t = threadIdx.x;
    const int lane = t & 63;
    const int w = t >> 6, wr = w >> 1, wc = w & 1;

    f32x4 acc[4][4];
    #pragma unroll
    for (int i = 0; i < 4; ++i)
        #pragma unroll
        for (int j = 0; j < 4; ++j) { acc[i][j].x = 0.f; acc[i][j].y = 0.f; acc[i][j].z = 0.f; acc[i][j].w = 0.f; }

    for (int k0 = 0; k0 < 1024; k0 += 32) {
        #pragma unroll
        for (int itr = 0; itr < 2; ++itr) {
            const int idx = itr * 256 + t;
            const int row = idx >> 2, kq = idx & 3;
            const float* s = A + (long)row * 1024 + k0 + kq * 8;
            const float4 f0 = *(const float4*)s, f1 = *(const float4*)(s + 4);
            uint4 p;
            p.x = cvth2(f0.x, f0.y); p.y = cvth2(f0.z, f0.w);
            p.z = cvth2(f1.x, f1.y); p.w = cvth2(f1.z, f1.w);
            *(uint4*)&As[row * BKP + kq * 8] = p;
        }
        #pragma unroll
        for (int itr = 0; itr < 2; ++itr) {
            const int idx = itr * 256 + t;
            const int row = idx >> 2, kq = idx & 3;
            const float* s = B + (long)(n0 + row) * 1024 + k0 + kq * 8;
            const float4 f0 = *(const float4*)s, f1 = *(const float4*)(s + 4);
            uint4 p;
            p.x = cvth2(f0.x, f0.y); p.y = cvth2(f0.z, f0.w);
            p.z = cvth2(f1.x, f1.y); p.w = cvth2(f1.z, f1.w);
            *(uint4*)&Bs[row * BKP + kq * 8] = p;
        }
        __syncthreads();

        f16x8 af[4], bfr[4];
        #pragma unroll
        for (int mi = 0; mi < 4; ++mi)
            af[mi] = *(const f16x8*)&As[(wr * 64 + mi * 16 + (lane & 15)) * BKP + (lane >> 4) * 8];
        #pragma unroll
        for (int ni = 0; ni < 4; ++ni)
            bfr[ni] = *(const f16x8*)&Bs[(wc * 64 + ni * 16 + (lane & 15)) * BKP + (lane >> 4) * 8];
        #pragma unroll
        for (int mi = 0; mi < 4; ++mi)
            #pragma unroll
            for (int ni = 0; ni < 4; ++ni)
                acc[mi][ni] = __builtin_amdgcn_mfma_f32_16x16x32_f16(af[mi], bfr[ni], acc[mi][ni], 0, 0, 0);
        __syncthreads();
    }

    // ---- column (over s) max: 10*acc ----
    float lm[4];
    #pragma unroll
    for (int ni = 0; ni < 4; ++ni) {
        float mx = -INFINITY;
        #pragma unroll
        for (int mi = 0; mi < 4; ++mi)
            #pragma unroll
            for (int j = 0; j < 4; ++j) mx = fmaxf(mx, acc[mi][ni][j]);
        mx *= 10.0f;
        mx = fmaxf(mx, __shfl_xor(mx, 16, 64));
        mx = fmaxf(mx, __shfl_xor(mx, 32, 64));
        lm[ni] = mx;
    }
    if ((lane >> 4) == 0) {
        #pragma unroll
        for (int ni = 0; ni < 4; ++ni) colmax[wr][wc * 64 + ni * 16 + lane] = lm[ni];
    }
    __syncthreads();
    float cm[4];
    #pragma unroll
    for (int ni = 0; ni < 4; ++ni) {
        const int c = wc * 64 + ni * 16 + (lane & 15);
        cm[ni] = fmaxf(colmax[0][c], colmax[1][c]);
    }
    if (wr == 0 && (lane >> 4) == 0) {
        #pragma unroll
        for (int ni = 0; ni < 4; ++ni)
            MiB[(long)z * 1024 + n0 + wc * 64 + ni * 16 + lane] = cm[ni];
    }
    // ---- ek = bf16(exp(10*acc - cm)) ----
    unsigned short* ekz = ekb + (long)z * (OUT_SIZE * IN_SIZE);
    #pragma unroll
    for (int mi = 0; mi < 4; ++mi) {
        #pragma unroll
        for (int ni = 0; ni < 4; ++ni) {
            const int col = n0 + wc * 64 + ni * 16 + (lane & 15);
            #pragma unroll
            for (int j = 0; j < 4; ++j) {
                const int row = wr * 64 + mi * 16 + (lane >> 4) * 4 + j;
                ekz[(long)row * 1024 + col] = bf16rne(__expf(fmaf(acc[mi][ni][j], 10.f, -cm[ni])));
            }
        }
    }
}

// ---------------------------------------------------------------------------
// x [n][i][d] fp32 -> xT [n][d][i] fp16 (RNE), 64x64 LDS tiles.
// ---------------------------------------------------------------------------
__global__ __launch_bounds__(256)
void transpose_cvt(const float* __restrict__ x, unsigned short* __restrict__ xT)
{
    const int n = blockIdx.z, i0 = blockIdx.y * 64, d0 = blockIdx.x * 64;
    const float* xs = x + (long)n * (IN_SIZE * IN_DIM);
    unsigned short* xo = xT + (long)n * (IN_SIZE * IN_DIM);
    __shared__ float tile[64][65];
    const int t = threadIdx.x;
    const int r = t >> 4, c4 = (t & 15) * 4;
    #pragma unroll
    for (int rr = 0; rr < 4; ++rr) {
        const float4 v = *(const float4*)(xs + (long)(i0 + rr * 16 + r) * IN_DIM + d0 + c4);
        *(float4*)&tile[rr * 16 + r][c4] = v;
    }
    __syncthreads();
    #pragma unroll
    for (int rr = 0; rr < 4; ++rr) {
        const int dl = rr * 16 + r;
        ushort4 o;
        o.x = cvth1(tile[c4 + 0][dl]); o.y = cvth1(tile[c4 + 1][dl]);
        o.z = cvth1(tile[c4 + 2][dl]); o.w = cvth1(tile[c4 + 3][dl]);
        *(ushort4*)(xo + (long)(d0 + dl) * IN_SIZE + i0 + c4) = o;
    }
}

// ---------------------------------------------------------------------------
// Sinkhorn v2: reads ek bf16 [128][1024] + Mi[1024] per tile; 10 register-
// resident iterations; outputs only the rank-1 factors eu[1024], ecv[128].
// T = ek * eu[i] * ecv[s] is materialized by GEMM2's staging.
// ---------------------------------------------------------------------------
__global__ __launch_bounds__(512)
void sinkhorn_t(const unsigned short* __restrict__ ekb,
                const float* __restrict__ MiB, float* __restrict__ euvB)
{
    const int b = blockIdx.x;
    const unsigned short* ekz = ekb + (long)b * (OUT_SIZE * IN_SIZE);
    const int t = threadIdx.x;
    const int lane = t & 63, w = t >> 6;

    __shared__ float part[8][1024];
    __shared__ float Mi_s[1024], eu_s[1024];
    __shared__ float v_s[128], ev_s[128];
    __shared__ float red8[8], red2[2];

    // ---- load ek into registers ----
    unsigned ek[16][8];
    #pragma unroll
    for (int r = 0; r < 16; ++r) {
        const unsigned short* rp = ekz + (long)(w * 16 + r) * 1024 + lane * 4;
        #pragma unroll
        for (int q = 0; q < 4; ++q) {
            const uint2 e = *(const uint2*)(rp + q * 256);
            ek[r][2 * q] = e.x; ek[r][2 * q + 1] = e.y;
        }
    }
    Mi_s[t]       = MiB[(long)b * 1024 + t];
    Mi_s[t + 512] = MiB[(long)b * 1024 + t + 512];
    if (t < 128) v_s[t] = 0.f;
    __syncthreads();

    const float A0 = -2.0794415416798357f;   // log(128/1024)
    float u_reg[2] = {0.f, 0.f};
    float wmx = 0.f;

    for (int it = 0; it < MAX_ITER; ++it) {
        // ---- vmx + ev ----
        if (t < 128) {
            float xv = v_s[t];
            #pragma unroll
            for (int m = 1; m < 64; m <<= 1) xv = fmaxf(xv, __shfl_xor(xv, m, 64));
            if (lane == 0) red2[w] = xv;
        }
        __syncthreads();
        const float vmx = fmaxf(red2[0], red2[1]);
        if (t < 128) ev_s[t] = __expf(v_s[t] - vmx);
        __syncthreads();

        // ---- u-pass: S[i] = sum_s ek*ev ----
        {
            f32x4 a4[4];
            #pragma unroll
            for (int q = 0; q < 4; ++q) { a4[q].x = 0.f; a4[q].y = 0.f; a4[q].z = 0.f; a4[q].w = 0.f; }
            #pragma unroll
            for (int r = 0; r < 16; ++r) {
                const float evv = ev_s[w * 16 + r];
                #pragma unroll
                for (int q = 0; q < 4; ++q) {
                    const unsigned e0 = ek[r][2 * q], e1 = ek[r][2 * q + 1];
                    a4[q].x = fmaf(__uint_as_float(e0 << 16),          evv, a4[q].x);
                    a4[q].y = fmaf(__uint_as_float(e0 & 0xffff0000u),  evv, a4[q].y);
                    a4[q].z = fmaf(__uint_as_float(e1 << 16),          evv, a4[q].z);
                    a4[q].w = fmaf(__uint_as_float(e1 & 0xffff0000u),  evv, a4[q].w);
                }
            }
            #pragma unroll
            for (int q = 0; q < 4; ++q) *(f32x4*)&part[w][q * 256 + lane * 4] = a4[q];
        }
        __syncthreads();
        {
            float wloc = -INFINITY, wv[2];
            #pragma unroll
            for (int h = 0; h < 2; ++h) {
                const int i = t + h * 512;
                float S = part[0][i];
                #pragma unroll
                for (int q = 1; q < 8; ++q) S += part[q][i];
                const float un = A0 - u_reg[h] - Mi_s[i] - vmx - __logf(S);
                u_reg[h] = un;
                wv[h] = Mi_s[i] + un;
                wloc = fmaxf(wloc, wv[h]);
            }
            #pragma unroll
            for (int m = 1; m < 64; m <<= 1) wloc = fmaxf(wloc, __shfl_xor(wloc, m, 64));
            if (lane == 0) red8[w] = wloc;
            __syncthreads();
            wmx = red8[0];
            #pragma unroll
            for (int q = 1; q < 8; ++q) wmx = fmaxf(wmx, red8[q]);
            eu_s[t]       = __expf(wv[0] - wmx);
            eu_s[t + 512] = __expf(wv[1] - wmx);
        }
        __syncthreads();

        // ---- v-pass: sum_i ek*eu, full in-wave i-butterfly ----
        {
            f32x4 eur[4];
            #pragma unroll
            for (int q = 0; q < 4; ++q) eur[q] = *(f32x4*)&eu_s[q * 256 + lane * 4];
            float cp[16];
            #pragma unroll
            for (int r = 0; r < 16; ++r) {
                float s0 = 0.f;
                #pragma unroll
                for (int q = 0; q < 4; ++q) {
                    const unsigned e0 = ek[r][2 * q], e1 = ek[r][2 * q + 1];
                    s0 = fmaf(__uint_as_float(e0 << 16),         eur[q].x, s0);
                    s0 = fmaf(__uint_as_float(e0 & 0xffff0000u), eur[q].y, s0);
                    s0 = fmaf(__uint_as_float(e1 << 16),         eur[q].z, s0);
                    s0 = fmaf(__uint_as_float(e1 & 0xffff0000u), eur[q].w, s0);
                }
                cp[r] = s0;
            }
            #pragma unroll
            for (int m = 1; m < 64; m <<= 1)
                #pragma unroll
                for (int r = 0; r < 16; ++r) cp[r] += __shfl_xor(cp[r], m, 64);
            if (lane == 0) {
                #pragma unroll
                for (int r = 0; r < 16; ++r)
                    v_s[w * 16 + r] = -v_s[w * 16 + r] - wmx - __logf(cp[r]);
            }
        }
        __syncthreads();
    }

    // ---- rank-1 factor output: eu (1024 f32) + ecv (128 f32) ----
    float* eb = euvB + (long)b * 1152;
    eb[t]       = eu_s[t];
    eb[t + 512] = eu_s[t + 512];
    if (t < 128) eb[1024 + t] = __expf(v_s[t] + wmx);
}

// ---------------------------------------------------------------------------
extern "C" void kernel_launch(void* const* d_in, const int* in_sizes, int n_in,
                              void* d_out, int out_size, void* d_ws, size_t ws_size,
                              hipStream_t stream)
{
    const float* x     = (const float*)d_in[0];   // [16][1024][1024]
    const float* otw   = (const float*)d_in[1];   // [4][128][1024]
    const float* lin_w = (const float*)d_in[2];   // [1024][4096]
    const float* lin_b = (const float*)d_in[3];   // [1024]
    float* out = (float*)d_out;                   // [16][128][1024] fp32 (8 MB)

    // ws (64 MB): [0,32M) xT fp16; [32M,48M) ek bf16 [64][128][1024];
    //             [48M,64M) feat fp16 [64][128][1024]
    unsigned short* xT   = (unsigned short*)d_ws;
    unsigned short* ekb  = xT + 16777216;
    unsigned short* feat = ekb + 8388608;
    // scratch inside d_out (fully overwritten by GEMM3): Mi [64][1024] f32,
    // euv [64][1152] f32 (eu 1024 + ecv 128)
    float* MiB  = (float*)d_out;
    float* euvB = MiB + 65536;

    // 0) x -> xT fp16
    transpose_cvt<<<dim3(16, 16, NB), 256, 0, stream>>>(x, xT);

    // 1) fused K-GEMM + colmax + exp -> ek bf16, Mi
    gemm1_exp<<<dim3(8, 1, 64), 256, 0, stream>>>(otw, x, ekb, MiB);

    // 2) Sinkhorn iterations -> eu/ecv factors
    sinkhorn_t<<<dim3(64), 512, 0, stream>>>(ekb, MiB, euvB);

    // 3) feat[b][s][d] = sum_i (ek*eu)[s][i] * xT[n][d][i], epilogue *ecv[s]
    mfma_gemm<2, false, 3, 4, false><<<dim3(8, 1, 64), 256, 0, stream>>>(
        ekb, xT, nullptr, feat, euvB,
        1024, 1024, 1024, 1024, 4,
        524288, 131072, 1048576, 0, 524288, 131072, 0, 1.0f);

    // 4) out[n][s][o] = relu(sum_{m,d} feat * lin_w[o][m*1024+d] + b[o])
    mfma_gemm<0, true, 2, 2, true><<<dim3(16, 1, NB), 256, 0, stream>>>(
        feat, lin_w, lin_b, out, nullptr,
        4096, 1024, 4096, 1024, 1,
        524288, 0, 0, 0, 131072, 0, 131072, 1.0f);
}

// Round 6
// 264.312 us; speedup vs baseline: 6.9738x; 1.1809x over previous
//
#include <hip/hip_runtime.h>
#include <math.h>

#define EPSV 0.1f
#define MAX_ITER 10
constexpr int NB       = 16;
constexpr int IN_SIZE  = 1024;
constexpr int IN_DIM   = 1024;
constexpr int HEADS    = 4;
constexpr int OUT_SIZE = 128;
constexpr int OUT_DIM  = 1024;

typedef __attribute__((ext_vector_type(8))) _Float16 f16x8;
typedef __attribute__((ext_vector_type(4))) float f32x4;

// fp32 -> fp16 RNE, packed pair
__device__ __forceinline__ unsigned cvth2(float lo, float hi) {
    _Float16 a = (_Float16)lo, b = (_Float16)hi;
    unsigned short ua = *(unsigned short*)&a, ub = *(unsigned short*)&b;
    return (unsigned)ua | ((unsigned)ub << 16);
}
__device__ __forceinline__ unsigned short cvth1(float f) {
    _Float16 a = (_Float16)f;
    return *(unsigned short*)&a;
}
// fp32 -> bf16 RNE single
__device__ __forceinline__ unsigned short bf16rne(float f) {
    unsigned a = __float_as_uint(f);
    return (unsigned short)((a + 0x7fffu + ((a >> 16) & 1u)) >> 16);
}

// ---------------------------------------------------------------------------
// MFMA fp16 GEMM, M fixed at 128. C = alpha*A*B^T (+variants).
// AMODE: 0 = A fp16 passthrough, 2 = A bf16-ek scaled by eu[i] during staging
// B_F32: B fp32 -> fp16 in-flight, else fp16 passthrough
// CMODE: 1 = fp16 store, 2 = f32 + bias + relu, 3 = fp16 * ecv[row],
//        4 = f32 raw store (split-K partial)
// AKBLK: A's K axis blocked as (k>>10) blocks of stride AkStride elems.
// ---------------------------------------------------------------------------
template<int AMODE, bool B_F32, int CMODE, int NF, bool AKBLK>
__global__ __launch_bounds__(256)
void mfma_gemm(const void* __restrict__ Ap, const void* __restrict__ Bp,
               const float* __restrict__ bias, void* __restrict__ Cp,
               const float* __restrict__ euv,
               int K, int lda, int ldb, int ldc, int div,
               long AsN, long AsM, long BsN, long BsM, long CsN, long CsM,
               long AkStride, float alpha)
{
    constexpr int BN  = NF * 32;
    constexpr int BKP = 40;            // padded LDS row stride (f16 elems)
    const int z = blockIdx.z;
    const long aoff = (long)(z / div) * AsN + (long)(z % div) * AsM;
    const long boff = (long)(z / div) * BsN + (long)(z % div) * BsM;
    const long coff = (long)(z / div) * CsN + (long)(z % div) * CsM;
    const int n0 = blockIdx.x * BN;

    __shared__ short As[128 * BKP];
    __shared__ short Bs[BN * BKP];
    __shared__ float ecv_s[128];

    const int t = threadIdx.x;
    const int lane = t & 63;
    const int w = t >> 6, wr = w >> 1, wc = w & 1;

    if (CMODE == 3 && t < 128) ecv_s[t] = euv[(long)z * 1152 + 1024 + t];

    f32x4 acc[4][NF];
    #pragma unroll
    for (int i = 0; i < 4; ++i)
        #pragma unroll
        for (int j = 0; j < NF; ++j) { acc[i][j].x = 0.f; acc[i][j].y = 0.f; acc[i][j].z = 0.f; acc[i][j].w = 0.f; }

    for (int k0 = 0; k0 < K; k0 += 32) {
        const long abase = AKBLK ? aoff + (long)(k0 >> 10) * AkStride + (k0 & 1023)
                                 : aoff + k0;
        const long bbase = boff + k0;
        // ---- stage A (128 x 32) ----
        #pragma unroll
        for (int itr = 0; itr < 2; ++itr) {
            const int idx = itr * 256 + t;
            const int row = idx >> 2, kq = idx & 3;
            uint4 p;
            if (AMODE == 2) {
                const uint4 e = *(const uint4*)((const short*)Ap + abase + (long)row * lda + kq * 8);
                const float* eup = euv + (long)z * 1152 + k0 + kq * 8;
                const float4 e0 = *(const float4*)eup, e1 = *(const float4*)(eup + 4);
                p.x = cvth2(__uint_as_float(e.x << 16) * e0.x, __uint_as_float(e.x & 0xffff0000u) * e0.y);
                p.y = cvth2(__uint_as_float(e.y << 16) * e0.z, __uint_as_float(e.y & 0xffff0000u) * e0.w);
                p.z = cvth2(__uint_as_float(e.z << 16) * e1.x, __uint_as_float(e.z & 0xffff0000u) * e1.y);
                p.w = cvth2(__uint_as_float(e.w << 16) * e1.z, __uint_as_float(e.w & 0xffff0000u) * e1.w);
            } else {
                p = *(const uint4*)((const short*)Ap + abase + (long)row * lda + kq * 8);
            }
            *(uint4*)&As[row * BKP + kq * 8] = p;
        }
        // ---- stage B (BN x 32) ----
        #pragma unroll
        for (int itr = 0; itr < BN / 64; ++itr) {
            const int idx = itr * 256 + t;
            const int row = idx >> 2, kq = idx & 3;
            uint4 p;
            if (B_F32) {
                const float* s = (const float*)Bp + bbase + (long)(n0 + row) * ldb + kq * 8;
                const float4 f0 = *(const float4*)s, f1 = *(const float4*)(s + 4);
                p.x = cvth2(f0.x, f0.y); p.y = cvth2(f0.z, f0.w);
                p.z = cvth2(f1.x, f1.y); p.w = cvth2(f1.z, f1.w);
            } else {
                p = *(const uint4*)((const short*)Bp + bbase + (long)(n0 + row) * ldb + kq * 8);
            }
            *(uint4*)&Bs[row * BKP + kq * 8] = p;
        }
        __syncthreads();

        f16x8 af[4], bfr[NF];
        #pragma unroll
        for (int mi = 0; mi < 4; ++mi)
            af[mi] = *(const f16x8*)&As[(wr * 64 + mi * 16 + (lane & 15)) * BKP + (lane >> 4) * 8];
        #pragma unroll
        for (int ni = 0; ni < NF; ++ni)
            bfr[ni] = *(const f16x8*)&Bs[(wc * (BN / 2) + ni * 16 + (lane & 15)) * BKP + (lane >> 4) * 8];
        #pragma unroll
        for (int mi = 0; mi < 4; ++mi)
            #pragma unroll
            for (int ni = 0; ni < NF; ++ni)
                acc[mi][ni] = __builtin_amdgcn_mfma_f32_16x16x32_f16(af[mi], bfr[ni], acc[mi][ni], 0, 0, 0);
        __syncthreads();
    }

    #pragma unroll
    for (int mi = 0; mi < 4; ++mi) {
        #pragma unroll
        for (int ni = 0; ni < NF; ++ni) {
            #pragma unroll
            for (int j = 0; j < 4; ++j) {
                const int row = wr * 64 + mi * 16 + (lane >> 4) * 4 + j;
                const int col = n0 + wc * (BN / 2) + ni * 16 + (lane & 15);
                float v = acc[mi][ni][j] * alpha;
                if (CMODE == 2) { v += bias[col]; v = fmaxf(v, 0.f); }
                if (CMODE == 3) v *= ecv_s[row];
                if (CMODE == 2 || CMODE == 4) ((float*)Cp)[coff + (long)row * ldc + col] = v;
                else ((unsigned short*)Cp)[coff + (long)row * ldc + col] = cvth1(v);
            }
        }
    }
}

// ---------------------------------------------------------------------------
// split-K reduce: out = relu(sum_ks partial[ks] + bias), float4 per thread.
// ---------------------------------------------------------------------------
__global__ __launch_bounds__(256)
void splitk_reduce(const float* __restrict__ part, const float* __restrict__ bias,
                   float* __restrict__ out)
{
    const long idx = ((long)blockIdx.x * 256 + threadIdx.x) * 4;
    const int o = (int)(idx & 1023);
    const float4 p0 = *(const float4*)(part + idx);
    const float4 p1 = *(const float4*)(part + 2097152 + idx);
    const float4 p2 = *(const float4*)(part + 2 * 2097152 + idx);
    const float4 p3 = *(const float4*)(part + 3 * 2097152 + idx);
    const float4 bv = *(const float4*)(bias + o);
    float4 r;
    r.x = fmaxf(p0.x + p1.x + p2.x + p3.x + bv.x, 0.f);
    r.y = fmaxf(p0.y + p1.y + p2.y + p3.y + bv.y, 0.f);
    r.z = fmaxf(p0.z + p1.z + p2.z + p3.z + bv.z, 0.f);
    r.w = fmaxf(p0.w + p1.w + p2.w + p3.w + bv.w, 0.f);
    *(float4*)(out + idx) = r;
}

// ---------------------------------------------------------------------------
// GEMM1 fused: K = 10 * otw[m] . x[n]^T for one (b, i-chunk); computes
// Mi[i] = max_s K (block holds ALL 128 s), writes ek = bf16(exp(K - Mi))
// and Mi. One block per (i-chunk 128, b).
// ---------------------------------------------------------------------------
__global__ __launch_bounds__(256)
void gemm1_exp(const float* __restrict__ otw, const float* __restrict__ x,
               unsigned short* __restrict__ ekb, float* __restrict__ MiB)
{
    constexpr int BKP = 40;
    const int z = blockIdx.z;                 // b = n*4+m
    const int nn = z >> 2, mm = z & 3;
    const float* A = otw + (long)mm * (OUT_SIZE * IN_DIM);   // [128][1024]
    const float* B = x   + (long)nn * (IN_SIZE * IN_DIM);    // [1024][1024]
    const int n0 = blockIdx.x * 128;          // i-chunk

    __shared__ short As[128 * BKP];
    __shared__ short Bs[128 * BKP];
    __shared__ float colmax[2][128];

    const int t = threadIdx.x;
    const int lane = t & 63;
    const int w = t >> 6, wr = w >> 1, wc = w & 1;

    f32x4 acc[4][4];
    #pragma unroll
    for (int i = 0; i < 4; ++i)
        #pragma unroll
        for (int j = 0; j < 4; ++j) { acc[i][j].x = 0.f; acc[i][j].y = 0.f; acc[i][j].z = 0.f; acc[i][j].w = 0.f; }

    for (int k0 = 0; k0 < 1024; k0 += 32) {
        #pragma unroll
        for (int itr = 0; itr < 2; ++itr) {
            const int idx = itr * 256 + t;
            const int row = idx >> 2, kq = idx & 3;
            const float* s = A + (long)row * 1024 + k0 + kq * 8;
            const float4 f0 = *(const float4*)s, f1 = *(const float4*)(s + 4);
            uint4 p;
            p.x = cvth2(f0.x, f0.y); p.y = cvth2(f0.z, f0.w);
            p.z = cvth2(f1.x, f1.y); p.w = cvth2(f1.z, f1.w);
            *(uint4*)&As[row * BKP + kq * 8] = p;
        }
        #pragma unroll
        for (int itr = 0; itr < 2; ++itr) {
            const int idx = itr * 256 + t;
            const int row = idx >> 2, kq = idx & 3;
            const float* s = B + (long)(n0 + row) * 1024 + k0 + kq * 8;
            const float4 f0 = *(const float4*)s, f1 = *(const float4*)(s + 4);
            uint4 p;
            p.x = cvth2(f0.x, f0.y); p.y = cvth2(f0.z, f0.w);
            p.z = cvth2(f1.x, f1.y); p.w = cvth2(f1.z, f1.w);
            *(uint4*)&Bs[row * BKP + kq * 8] = p;
        }
        __syncthreads();

        f16x8 af[4], bfr[4];
        #pragma unroll
        for (int mi = 0; mi < 4; ++mi)
            af[mi] = *(const f16x8*)&As[(wr * 64 + mi * 16 + (lane & 15)) * BKP + (lane >> 4) * 8];
        #pragma unroll
        for (int ni = 0; ni < 4; ++ni)
            bfr[ni] = *(const f16x8*)&Bs[(wc * 64 + ni * 16 + (lane & 15)) * BKP + (lane >> 4) * 8];
        #pragma unroll
        for (int mi = 0; mi < 4; ++mi)
            #pragma unroll
            for (int ni = 0; ni < 4; ++ni)
                acc[mi][ni] = __builtin_amdgcn_mfma_f32_16x16x32_f16(af[mi], bfr[ni], acc[mi][ni], 0, 0, 0);
        __syncthreads();
    }

    // ---- column (over s) max: 10*acc ----
    float lm[4];
    #pragma unroll
    for (int ni = 0; ni < 4; ++ni) {
        float mx = -INFINITY;
        #pragma unroll
        for (int mi = 0; mi < 4; ++mi)
            #pragma unroll
            for (int j = 0; j < 4; ++j) mx = fmaxf(mx, acc[mi][ni][j]);
        mx *= 10.0f;
        mx = fmaxf(mx, __shfl_xor(mx, 16, 64));
        mx = fmaxf(mx, __shfl_xor(mx, 32, 64));
        lm[ni] = mx;
    }
    if ((lane >> 4) == 0) {
        #pragma unroll
        for (int ni = 0; ni < 4; ++ni) colmax[wr][wc * 64 + ni * 16 + lane] = lm[ni];
    }
    __syncthreads();
    float cm[4];
    #pragma unroll
    for (int ni = 0; ni < 4; ++ni) {
        const int c = wc * 64 + ni * 16 + (lane & 15);
        cm[ni] = fmaxf(colmax[0][c], colmax[1][c]);
    }
    if (wr == 0 && (lane >> 4) == 0) {
        #pragma unroll
        for (int ni = 0; ni < 4; ++ni)
            MiB[(long)z * 1024 + n0 + wc * 64 + ni * 16 + lane] = cm[ni];
    }
    // ---- ek = bf16(exp(10*acc - cm)) ----
    unsigned short* ekz = ekb + (long)z * (OUT_SIZE * IN_SIZE);
    #pragma unroll
    for (int mi = 0; mi < 4; ++mi) {
        #pragma unroll
        for (int ni = 0; ni < 4; ++ni) {
            const int col = n0 + wc * 64 + ni * 16 + (lane & 15);
            #pragma unroll
            for (int j = 0; j < 4; ++j) {
                const int row = wr * 64 + mi * 16 + (lane >> 4) * 4 + j;
                ekz[(long)row * 1024 + col] = bf16rne(__expf(fmaf(acc[mi][ni][j], 10.f, -cm[ni])));
            }
        }
    }
}

// ---------------------------------------------------------------------------
// x [n][i][d] fp32 -> xT [n][d][i] fp16 (RNE), 64x64 LDS tiles.
// ---------------------------------------------------------------------------
__global__ __launch_bounds__(256)
void transpose_cvt(const float* __restrict__ x, unsigned short* __restrict__ xT)
{
    const int n = blockIdx.z, i0 = blockIdx.y * 64, d0 = blockIdx.x * 64;
    const float* xs = x + (long)n * (IN_SIZE * IN_DIM);
    unsigned short* xo = xT + (long)n * (IN_SIZE * IN_DIM);
    __shared__ float tile[64][65];
    const int t = threadIdx.x;
    const int r = t >> 4, c4 = (t & 15) * 4;
    #pragma unroll
    for (int rr = 0; rr < 4; ++rr) {
        const float4 v = *(const float4*)(xs + (long)(i0 + rr * 16 + r) * IN_DIM + d0 + c4);
        *(float4*)&tile[rr * 16 + r][c4] = v;
    }
    __syncthreads();
    #pragma unroll
    for (int rr = 0; rr < 4; ++rr) {
        const int dl = rr * 16 + r;
        ushort4 o;
        o.x = cvth1(tile[c4 + 0][dl]); o.y = cvth1(tile[c4 + 1][dl]);
        o.z = cvth1(tile[c4 + 2][dl]); o.w = cvth1(tile[c4 + 3][dl]);
        *(ushort4*)(xo + (long)(d0 + dl) * IN_SIZE + i0 + c4) = o;
    }
}

// ---------------------------------------------------------------------------
// Sinkhorn v3: 1024 threads (16 waves). Wave w owns s-rows w*8..w*8+7
// (ek[8][8] bf16 pairs = 64 VGPRs); thread t owns i = t (u is a scalar reg).
// Reads ek bf16 + Mi; 10 register-resident iterations; outputs rank-1
// factors eu[1024], ecv[128]. T = ek * eu[i] * ecv[s] applied by GEMM2.
// ---------------------------------------------------------------------------
__global__ __launch_bounds__(1024)
void sinkhorn_t(const unsigned short* __restrict__ ekb,
                const float* __restrict__ MiB, float* __restrict__ euvB)
{
    const int b = blockIdx.x;
    const unsigned short* ekz = ekb + (long)b * (OUT_SIZE * IN_SIZE);
    const int t = threadIdx.x;
    const int lane = t & 63, w = t >> 6;     // w in [0,16)

    __shared__ float part[16][1024];
    __shared__ float eu_s[1024];
    __shared__ float v_s[128], ev_s[128];
    __shared__ float red16[16], red16v[16];

    // ---- load ek into registers ----
    unsigned ek[8][8];
    #pragma unroll
    for (int r = 0; r < 8; ++r) {
        const unsigned short* rp = ekz + (long)(w * 8 + r) * 1024 + lane * 4;
        #pragma unroll
        for (int q = 0; q < 4; ++q) {
            const uint2 e = *(const uint2*)(rp + q * 256);
            ek[r][2 * q] = e.x; ek[r][2 * q + 1] = e.y;
        }
    }
    const float mi_t = MiB[(long)b * 1024 + t];
    if (t < 128) v_s[t] = 0.f;
    if (t < 16) red16v[t] = 0.f;
    __syncthreads();

    const float A0 = -2.0794415416798357f;   // log(128/1024)
    float u_reg = 0.f;
    float wmx = 0.f;

    for (int it = 0; it < MAX_ITER; ++it) {
        // ---- vmx from red16v (written before last barrier), ev ----
        float vmx = red16v[0];
        #pragma unroll
        for (int q = 1; q < 16; ++q) vmx = fmaxf(vmx, red16v[q]);
        if (t < 128) ev_s[t] = __expf(v_s[t] - vmx);
        __syncthreads();

        // ---- u-pass partials: part[w][i] = sum_{r<8} ek*ev ----
        {
            f32x4 a4[4];
            #pragma unroll
            for (int q = 0; q < 4; ++q) { a4[q].x = 0.f; a4[q].y = 0.f; a4[q].z = 0.f; a4[q].w = 0.f; }
            #pragma unroll
            for (int r = 0; r < 8; ++r) {
                const float evv = ev_s[w * 8 + r];
                #pragma unroll
                for (int q = 0; q < 4; ++q) {
                    const unsigned e0 = ek[r][2 * q], e1 = ek[r][2 * q + 1];
                    a4[q].x = fmaf(__uint_as_float(e0 << 16),          evv, a4[q].x);
                    a4[q].y = fmaf(__uint_as_float(e0 & 0xffff0000u),  evv, a4[q].y);
                    a4[q].z = fmaf(__uint_as_float(e1 << 16),          evv, a4[q].z);
                    a4[q].w = fmaf(__uint_as_float(e1 & 0xffff0000u),  evv, a4[q].w);
                }
            }
            #pragma unroll
            for (int q = 0; q < 4; ++q) *(f32x4*)&part[w][q * 256 + lane * 4] = a4[q];
        }
        __syncthreads();

        // ---- S + u update (thread t owns i = t) ----
        float wv;
        {
            float S = part[0][t];
            #pragma unroll
            for (int q = 1; q < 16; ++q) S += part[q][t];
            const float un = A0 - u_reg - mi_t - vmx - __logf(S);
            u_reg = un;
            wv = mi_t + un;
            float wloc = wv;
            #pragma unroll
            for (int m = 1; m < 64; m <<= 1) wloc = fmaxf(wloc, __shfl_xor(wloc, m, 64));
            if (lane == 0) red16[w] = wloc;
        }
        __syncthreads();
        wmx = red16[0];
        #pragma unroll
        for (int q = 1; q < 16; ++q) wmx = fmaxf(wmx, red16[q]);
        eu_s[t] = __expf(wv - wmx);
        __syncthreads();

        // ---- v-pass: cp[r] = sum_i ek*eu, in-wave butterfly ----
        {
            f32x4 eur[4];
            #pragma unroll
            for (int q = 0; q < 4; ++q) eur[q] = *(f32x4*)&eu_s[q * 256 + lane * 4];
            float cp[8];
            #pragma unroll
            for (int r = 0; r < 8; ++r) {
                float s0 = 0.f;
                #pragma unroll
                for (int q = 0; q < 4; ++q) {
                    const unsigned e0 = ek[r][2 * q], e1 = ek[r][2 * q + 1];
                    s0 = fmaf(__uint_as_float(e0 << 16),         eur[q].x, s0);
                    s0 = fmaf(__uint_as_float(e0 & 0xffff0000u), eur[q].y, s0);
                    s0 = fmaf(__uint_as_float(e1 << 16),         eur[q].z, s0);
                    s0 = fmaf(__uint_as_float(e1 & 0xffff0000u), eur[q].w, s0);
                }
                cp[r] = s0;
            }
            #pragma unroll
            for (int m = 1; m < 64; m <<= 1)
                #pragma unroll
                for (int r = 0; r < 8; ++r) cp[r] += __shfl_xor(cp[r], m, 64);
            if (lane == 0) {
                float vm = -INFINITY;
                #pragma unroll
                for (int r = 0; r < 8; ++r) {
                    const float vn = -v_s[w * 8 + r] - wmx - __logf(cp[r]);
                    v_s[w * 8 + r] = vn;
                    vm = fmaxf(vm, vn);
                }
                red16v[w] = vm;
            }
        }
        __syncthreads();
    }

    // ---- rank-1 factor output: eu (1024 f32) + ecv (128 f32) ----
    float* eb = euvB + (long)b * 1152;
    eb[t] = eu_s[t];
    if (t < 128) eb[1024 + t] = __expf(v_s[t] + wmx);
}

// ---------------------------------------------------------------------------
extern "C" void kernel_launch(void* const* d_in, const int* in_sizes, int n_in,
                              void* d_out, int out_size, void* d_ws, size_t ws_size,
                              hipStream_t stream)
{
    const float* x     = (const float*)d_in[0];   // [16][1024][1024]
    const float* otw   = (const float*)d_in[1];   // [4][128][1024]
    const float* lin_w = (const float*)d_in[2];   // [1024][4096]
    const float* lin_b = (const float*)d_in[3];   // [1024]
    float* out = (float*)d_out;                   // [16][128][1024] fp32 (8 MB)

    // ws (64 MB): [0,32M) xT fp16 (dead after GEMM2 -> reused as split-K partials)
    //             [32M,48M) ek bf16 [64][128][1024]; [48M,64M) feat fp16
    unsigned short* xT   = (unsigned short*)d_ws;
    unsigned short* ekb  = xT + 16777216;
    unsigned short* feat = ekb + 8388608;
    float* partial = (float*)d_ws;                // [4][16][128][1024] f32 = 32 MB
    // scratch inside d_out (fully overwritten by splitk_reduce): Mi, euv
    float* MiB  = (float*)d_out;
    float* euvB = MiB + 65536;

    // 0) x -> xT fp16
    transpose_cvt<<<dim3(16, 16, NB), 256, 0, stream>>>(x, xT);

    // 1) fused K-GEMM + colmax + exp -> ek bf16, Mi
    gemm1_exp<<<dim3(8, 1, 64), 256, 0, stream>>>(otw, x, ekb, MiB);

    // 2) Sinkhorn iterations -> eu/ecv factors
    sinkhorn_t<<<dim3(64), 1024, 0, stream>>>(ekb, MiB, euvB);

    // 3) feat[b][s][d] = sum_i (ek*eu)[s][i] * xT[n][d][i], epilogue *ecv[s]
    mfma_gemm<2, false, 3, 4, false><<<dim3(8, 1, 64), 256, 0, stream>>>(
        ekb, xT, nullptr, feat, euvB,
        1024, 1024, 1024, 1024, 4,
        524288, 131072, 1048576, 0, 524288, 131072, 0, 1.0f);

    // 4) split-K x4 GEMM3: partial[ks][n][s][o] = feat[n][:, ks-block] . lin_w^T
    //    z = ks*16 + n
    mfma_gemm<0, true, 4, 2, false><<<dim3(16, 1, 64), 256, 0, stream>>>(
        feat, lin_w, nullptr, partial, nullptr,
        1024, 1024, 4096, 1024, 16,
        131072, 524288, 1024, 0, 2097152, 131072, 0, 1.0f);

    // 5) out = relu(sum_ks partial + bias)
    splitk_reduce<<<dim3(2048), 256, 0, stream>>>(partial, lin_b, out);
}